// Round 3
// 680.224 us; speedup vs baseline: 1.0101x; 1.0101x over previous
//
#include <hip/hip_runtime.h>
#include <math.h>

#define B 32
#define S 4096
#define H 1024
#define NCHUNK 32                         // pass-1 blocks per batch
#define ROWS_PER_BLOCK (S / NCHUNK)       // 128
#define ROWS_PER_WAVE (ROWS_PER_BLOCK/4)  // 32
#define NPAIRS (ROWS_PER_WAVE/2)          // 16 pairs of 2 rows
#define PSTRIDE 1040                      // 1024 c + m + l, padded to 16B mult

typedef float fx4 __attribute__((ext_vector_type(4)));

// 16-element dot as two independent 8-deep FMA chains (halves dep latency)
__device__ __forceinline__ float dot16(const fx4 e0, const fx4 e1,
                                       const fx4 e2, const fx4 e3,
                                       const fx4 d0, const fx4 d1,
                                       const fx4 d2, const fx4 d3)
{
    float pa = e0.x * d0.x;
    pa = fmaf(e0.y, d0.y, pa); pa = fmaf(e0.z, d0.z, pa); pa = fmaf(e0.w, d0.w, pa);
    pa = fmaf(e1.x, d1.x, pa); pa = fmaf(e1.y, d1.y, pa);
    pa = fmaf(e1.z, d1.z, pa); pa = fmaf(e1.w, d1.w, pa);
    float pb = e2.x * d2.x;
    pb = fmaf(e2.y, d2.y, pb); pb = fmaf(e2.z, d2.z, pb); pb = fmaf(e2.w, d2.w, pb);
    pb = fmaf(e3.x, d3.x, pb); pb = fmaf(e3.y, d3.y, pb);
    pb = fmaf(e3.z, d3.z, pb); pb = fmaf(e3.w, d3.w, pb);
    return pa + pb;
}

__device__ __forceinline__ fx4 fma4(const float s, const fx4 v, fx4 acc) {
    acc.x = fmaf(s, v.x, acc.x); acc.y = fmaf(s, v.y, acc.y);
    acc.z = fmaf(s, v.z, acc.z); acc.w = fmaf(s, v.w, acc.w);
    return acc;
}

// Issue the 8 loads for one row-pair (rows ROW, ROW+1 of batch b's enc).
#define LOAD_PAIR(E0, E1, E2, E3, E4, E5, E6, E7, ROW)                        \
    do {                                                                      \
        const fx4* ep0_ = (const fx4*)(enc_b + (size_t)(ROW) * H);            \
        const fx4* ep1_ = (const fx4*)(enc_b + (size_t)((ROW) + 1) * H);      \
        E0 = ep0_[lane];       E1 = ep0_[lane + 64];                          \
        E2 = ep0_[lane + 128]; E3 = ep0_[lane + 192];                         \
        E4 = ep1_[lane];       E5 = ep1_[lane + 64];                          \
        E6 = ep1_[lane + 128]; E7 = ep1_[lane + 192];                         \
    } while (0)

// Consume one row-pair: dot, butterfly-reduce, score store, online softmax,
// weighted accumulate.
#define CONSUME_PAIR(E0, E1, E2, E3, E4, E5, E6, E7, ROW)                     \
    do {                                                                      \
        float p0 = dot16(E0, E1, E2, E3, ds0, ds1, ds2, ds3);                 \
        float p1 = dot16(E4, E5, E6, E7, ds0, ds1, ds2, ds3);                 \
        _Pragma("unroll")                                                     \
        for (int st_ = 32; st_ >= 1; st_ >>= 1) {                             \
            p0 += __shfl_xor(p0, st_);                                        \
            p1 += __shfl_xor(p1, st_);                                        \
        }                                                                     \
        if (lane == 0) {                                                      \
            float2 sv_ = {p0, p1};                                            \
            *(float2*)(scores + (size_t)b * S + (ROW)) = sv_;                 \
        }                                                                     \
        const float gm_ = fmaxf(p0, p1);                                      \
        if (gm_ > m) {   /* wave-uniform branch */                            \
            const float alpha_ = __expf(m - gm_); /* exp(-inf)=0 first time */\
            m = gm_;                                                          \
            l *= alpha_;                                                      \
            a0 *= alpha_; a1 *= alpha_; a2 *= alpha_; a3 *= alpha_;           \
        }                                                                     \
        const float w0_ = __expf(p0 - m);                                     \
        const float w1_ = __expf(p1 - m);                                     \
        l += w0_ + w1_;                                                       \
        a0 = fma4(w0_, E0, fma4(w1_, E4, a0));                                \
        a1 = fma4(w0_, E1, fma4(w1_, E5, a1));                                \
        a2 = fma4(w0_, E2, fma4(w1_, E6, a2));                                \
        a3 = fma4(w0_, E3, fma4(w1_, E7, a3));                                \
    } while (0)

// Pass 1: fused scores + online softmax + weighted context accumulation.
// One wave owns 32 contiguous s-rows, processed as 16 pairs with a
// register ping-pong (eA/eB) so ~8KB of loads stay in flight per wave
// while the previous pair's compute runs. No VGPR cap: the ~115-reg live
// set must not spill (round-1 lesson: the forced 128 cap caused scratch
// spills that serialized every group).
__global__ __launch_bounds__(256) void attn_pass1(
    const float* __restrict__ dec, const float* __restrict__ enc,
    float* __restrict__ scores, float* __restrict__ part)
{
    const int blk   = blockIdx.x;
    const int b     = blk / NCHUNK;
    const int chunk = blk % NCHUNK;
    const int lane  = threadIdx.x & 63;
    const int w     = threadIdx.x >> 6;

    const fx4* dsp = (const fx4*)(dec + (size_t)b * H);
    const fx4 ds0 = dsp[lane];
    const fx4 ds1 = dsp[lane + 64];
    const fx4 ds2 = dsp[lane + 128];
    const fx4 ds3 = dsp[lane + 192];

    float m = -INFINITY, l = 0.f;
    fx4 a0 = {0.f, 0.f, 0.f, 0.f}, a1 = a0, a2 = a0, a3 = a0;

    const int row0 = chunk * ROWS_PER_BLOCK + w * ROWS_PER_WAVE;
    const float* enc_b = enc + (size_t)b * S * H;

    fx4 eA0, eA1, eA2, eA3, eA4, eA5, eA6, eA7;
    fx4 eB0, eB1, eB2, eB3, eB4, eB5, eB6, eB7;

    // Prologue: issue pair 0 into eA.
    LOAD_PAIR(eA0, eA1, eA2, eA3, eA4, eA5, eA6, eA7, row0);

    // 16 pairs, two per iteration (ping-pong).
    for (int p = 0; p < NPAIRS; p += 2) {
        const int rowA = row0 + p * 2;
        const int rowB = rowA + 2;
        // Issue pair p+1 into eB, then consume eA.
        LOAD_PAIR(eB0, eB1, eB2, eB3, eB4, eB5, eB6, eB7, rowB);
        CONSUME_PAIR(eA0, eA1, eA2, eA3, eA4, eA5, eA6, eA7, rowA);

        // Issue pair p+2 into eA (if any), then consume eB.
        if (p + 2 < NPAIRS) {
            LOAD_PAIR(eA0, eA1, eA2, eA3, eA4, eA5, eA6, eA7, rowB + 2);
        }
        CONSUME_PAIR(eB0, eB1, eB2, eB3, eB4, eB5, eB6, eB7, rowB);
    }

    // Combine the 4 wave partials -> one block partial
    __shared__ float sm[4], sl[4];
    __shared__ float sc[4][1024];
    if (lane == 0) { sm[w] = m; sl[w] = l; }
    *(fx4*)&sc[w][lane * 4]       = a0;
    *(fx4*)&sc[w][lane * 4 + 256] = a1;
    *(fx4*)&sc[w][lane * 4 + 512] = a2;
    *(fx4*)&sc[w][lane * 4 + 768] = a3;
    __syncthreads();

    const float M   = fmaxf(fmaxf(sm[0], sm[1]), fmaxf(sm[2], sm[3]));
    const float al0 = __expf(sm[0] - M), al1 = __expf(sm[1] - M);
    const float al2 = __expf(sm[2] - M), al3 = __expf(sm[3] - M);
    const float Lb  = sl[0] * al0 + sl[1] * al1 + sl[2] * al2 + sl[3] * al3;

    const int t = threadIdx.x;
    const fx4 c0 = *(const fx4*)&sc[0][t * 4];
    const fx4 c1 = *(const fx4*)&sc[1][t * 4];
    const fx4 c2 = *(const fx4*)&sc[2][t * 4];
    const fx4 c3 = *(const fx4*)&sc[3][t * 4];
    const fx4 cp = c0 * al0 + c1 * al1 + c2 * al2 + c3 * al3;

    float* pb = part + (size_t)blk * PSTRIDE;
    *(fx4*)&pb[t * 4] = cp;
    if (t == 0) { pb[1024] = M; pb[1025] = Lb; }
}

// Pass 2: reduce the 32 per-block partials of each batch to global (M, L),
// then emit context (h-slice) and attn (s-slice).
__global__ __launch_bounds__(256) void attn_pass2(
    const float* __restrict__ scores, const float* __restrict__ part,
    float* __restrict__ out)
{
    const int b = blockIdx.x >> 2;
    const int j = blockIdx.x & 3;
    const int t = threadIdx.x;
    const float* pbase = part + (size_t)b * NCHUNK * PSTRIDE;

    float M = -INFINITY;
    for (int i = 0; i < NCHUNK; ++i)
        M = fmaxf(M, pbase[i * PSTRIDE + 1024]);
    float L = 0.f;
    for (int i = 0; i < NCHUNK; ++i)
        L += pbase[i * PSTRIDE + 1025] * __expf(pbase[i * PSTRIDE + 1024] - M);
    const float invL = 1.f / L;

    // context slice: h = j*256 + t
    const int h = j * 256 + t;
    float acc = 0.f;
    for (int i = 0; i < NCHUNK; ++i)
        acc = fmaf(__expf(pbase[i * PSTRIDE + 1024] - M),
                   pbase[i * PSTRIDE + h], acc);
    out[(size_t)b * H + h] = acc * invL;

    // attn slice: s in [j*1024, (j+1)*1024)
    float* attn_out = out + (size_t)B * H;
    for (int k = 0; k < 4; ++k) {
        const int s = j * 1024 + k * 256 + t;
        attn_out[(size_t)b * S + s] =
            __expf(scores[(size_t)b * S + s] - M) * invL;
    }
}

extern "C" void kernel_launch(void* const* d_in, const int* in_sizes, int n_in,
                              void* d_out, int out_size, void* d_ws, size_t ws_size,
                              hipStream_t stream) {
    const float* dec = (const float*)d_in[0];   // (32, 1024)
    const float* enc = (const float*)d_in[1];   // (32, 4096, 1024)
    float* out = (float*)d_out;                 // context(32*1024) ++ attn(32*4096)
    float* ws  = (float*)d_ws;
    float* scores = ws;                         // B*S floats
    float* part   = ws + (size_t)B * S;         // B*NCHUNK*PSTRIDE floats (~4.3 MB)

    attn_pass1<<<B * NCHUNK, 256, 0, stream>>>(dec, enc, scores, part);
    attn_pass2<<<B * 4, 256, 0, stream>>>(scores, part, out);
}